// Round 1
// baseline (787.736 us; speedup 1.0000x reference)
//
#include <hip/hip_runtime.h>
#include <stdint.h>

// Problem constants (B=8,T=8192,C=256,E=64, top-2, cap_factor=1.25)
#define N_TOK   65536
#define S_SLOTS 131072
#define NEXP    64
#define CDIM    256
#define CAP     2560          // int(1.25 * 131072 / 64)

typedef unsigned short u16;
typedef float    fvec4  __attribute__((ext_vector_type(4)));
typedef float    f32x4  __attribute__((ext_vector_type(4)));
typedef __bf16   bf16x8 __attribute__((ext_vector_type(8)));
typedef unsigned short u16x4 __attribute__((ext_vector_type(4)));

typedef __attribute__((address_space(1))) const void gvoid_t;
typedef __attribute__((address_space(3))) void       svoid_t;

__device__ __forceinline__ u16 f2bf(float f) {          // RNE float->bf16
  uint32_t u = __builtin_bit_cast(uint32_t, f);
  u += 0x7fffu + ((u >> 16) & 1u);
  return (u16)(u >> 16);
}
__device__ __forceinline__ float bf2f(u16 h) {
  return __builtin_bit_cast(float, (uint32_t)h << 16);
}
__device__ __forceinline__ void gload16(const void* g, void* l) {
  __builtin_amdgcn_global_load_lds(
      reinterpret_cast<gvoid_t*>(reinterpret_cast<uintptr_t>(g)),
      reinterpret_cast<svoid_t*>(reinterpret_cast<uintptr_t>(l)),
      16, 0, 0);
}

// ---------------------------------------------------------------------------
// Kernel 1: gating. fp32 GEMM (64 tok x 64 exp, K=256) + softmax + top2 +
// x->bf16 conversion + load partials. Block=256 thr, 64 tokens/block.
// ---------------------------------------------------------------------------
__global__ __launch_bounds__(256) void gating_kernel(
    const float* __restrict__ x, const float* __restrict__ Wg,
    u16* __restrict__ x_bf16, float* __restrict__ slot_score,
    int* __restrict__ slot_eid, float* __restrict__ load_g)
{
  __shared__ float W_s[64 * 64];    // [kk][e]
  __shared__ float A_s[64 * 68];    // [m][kk] pad->68 (2-way max on frag reads)
  __shared__ float L_s[64 * 65];    // logits [m][e]
  __shared__ float loadp[4 * 64];

  const int t  = threadIdx.x;
  const int m0 = blockIdx.x * 64;
  const int ty = t >> 4, tx = t & 15;   // thread computes tokens ty*4+j, experts tx*4+i

  float acc[4][4];
#pragma unroll
  for (int j = 0; j < 4; ++j)
#pragma unroll
    for (int i = 0; i < 4; ++i) acc[j][i] = 0.f;

  for (int kt = 0; kt < 4; ++kt) {
    const int k0 = kt * 64;
#pragma unroll
    for (int p = 0; p < 4; ++p) {     // stage W tile [64k][64e]
      int idx = p * 1024 + t * 4;
      int kk = idx >> 6, e = idx & 63;
      *(fvec4*)&W_s[kk * 64 + e] = *(const fvec4*)&Wg[(size_t)(k0 + kk) * 64 + e];
    }
#pragma unroll
    for (int p = 0; p < 4; ++p) {     // stage A tile [64m][64k] + write x_bf16
      int idx = p * 1024 + t * 4;
      int m = idx >> 6, k = idx & 63;
      fvec4 v = *(const fvec4*)&x[(size_t)(m0 + m) * 256 + k0 + k];
      *(fvec4*)&A_s[m * 68 + k] = v;
      u16x4 h;
      h.x = f2bf(v.x); h.y = f2bf(v.y); h.z = f2bf(v.z); h.w = f2bf(v.w);
      *(u16x4*)&x_bf16[(size_t)(m0 + m) * 256 + k0 + k] = h;
    }
    __syncthreads();
#pragma unroll
    for (int k4 = 0; k4 < 16; ++k4) {
      fvec4 av[4], bv[4];
#pragma unroll
      for (int j = 0; j < 4; ++j)
        av[j] = *(const fvec4*)&A_s[(ty * 4 + j) * 68 + k4 * 4];
#pragma unroll
      for (int kk = 0; kk < 4; ++kk)
        bv[kk] = *(const fvec4*)&W_s[(k4 * 4 + kk) * 64 + tx * 4];
#pragma unroll
      for (int j = 0; j < 4; ++j)
#pragma unroll
        for (int i = 0; i < 4; ++i) {   // k ascending -> deterministic fp32 order
          acc[j][i] = fmaf(av[j][0], bv[0][i], acc[j][i]);
          acc[j][i] = fmaf(av[j][1], bv[1][i], acc[j][i]);
          acc[j][i] = fmaf(av[j][2], bv[2][i], acc[j][i]);
          acc[j][i] = fmaf(av[j][3], bv[3][i], acc[j][i]);
        }
    }
    __syncthreads();
  }

#pragma unroll
  for (int j = 0; j < 4; ++j)
#pragma unroll
    for (int i = 0; i < 4; ++i)
      L_s[(ty * 4 + j) * 65 + tx * 4 + i] = acc[j][i];
  __syncthreads();

  const int wave = t >> 6, lane = t & 63;
  float lsum = 0.f;
  for (int it = 0; it < 16; ++it) {
    int tl = wave * 16 + it;
    float lg = L_s[tl * 65 + lane];
    float mx = lg;
#pragma unroll
    for (int off = 1; off < 64; off <<= 1) mx = fmaxf(mx, __shfl_xor(mx, off));
    float pe = expf(lg - mx);
    float sm = pe;
#pragma unroll
    for (int off = 1; off < 64; off <<= 1) sm += __shfl_xor(sm, off);
    float p = pe / sm;                 // gate prob (no renorm, matches ref)
    lsum += p;
    // top-1: max value, lowest index on ties (matches lax.top_k)
    float v1 = p; int i1 = lane;
#pragma unroll
    for (int off = 1; off < 64; off <<= 1) {
      float vo = __shfl_xor(v1, off); int io = __shfl_xor(i1, off);
      if (vo > v1 || (vo == v1 && io < i1)) { v1 = vo; i1 = io; }
    }
    float pm = (lane == i1) ? -1.f : p;   // gates > 0, -1 is a safe sentinel
    float v2 = pm; int i2 = lane;
#pragma unroll
    for (int off = 1; off < 64; off <<= 1) {
      float vo = __shfl_xor(v2, off); int io = __shfl_xor(i2, off);
      if (vo > v2 || (vo == v2 && io < i2)) { v2 = vo; i2 = io; }
    }
    if (lane == 0) {
      int tg = m0 + tl;
      slot_eid[2 * tg]     = i1;
      slot_eid[2 * tg + 1] = i2;
      slot_score[2 * tg]     = v1;
      slot_score[2 * tg + 1] = v2;
    }
  }
  loadp[wave * 64 + lane] = lsum;
  __syncthreads();
  if (t < 64) {
    float s = loadp[t] + loadp[64 + t] + loadp[128 + t] + loadp[192 + t];
    atomicAdd(&load_g[t], s);
  }
}

// ---------------------------------------------------------------------------
// Kernel 2: W_experts [e][k][d] fp32 -> WT [e][d][k] bf16 (K-fast for MFMA B).
// Grid: 64 experts x 16 (64x64) tiles.
// ---------------------------------------------------------------------------
__global__ __launch_bounds__(256) void wtrans_kernel(
    const float* __restrict__ W, u16* __restrict__ WT)
{
  __shared__ float tile[64 * 65];
  const int b = blockIdx.x;
  const int e = b >> 4, tt = b & 15;
  const int k0 = (tt >> 2) * 64, d0 = (tt & 3) * 64;
  const int t = threadIdx.x;
  const int j = t & 63, i0 = t >> 6;
  const float* We = W + (size_t)e * 65536;
#pragma unroll
  for (int p = 0; p < 16; ++p) {
    int i = p * 4 + i0;
    tile[i * 65 + j] = We[(size_t)(k0 + i) * 256 + d0 + j];   // coalesced on d
  }
  __syncthreads();
  u16* WTe = WT + (size_t)e * 65536;
#pragma unroll
  for (int p = 0; p < 16; ++p) {
    int d = p * 4 + i0;
    WTe[(size_t)(d0 + d) * 256 + k0 + j] = f2bf(tile[j * 65 + d]); // coalesced on k
  }
}

// ---------------------------------------------------------------------------
// Kernel 3: stable FIFO compaction. One wave per expert; ballot-rank over
// slots in ascending order (exactly the reference's cumsum rank).
// ---------------------------------------------------------------------------
__global__ __launch_bounds__(64) void compact_kernel(
    const int* __restrict__ slot_eid, int* __restrict__ slot2buf,
    int* __restrict__ row_token)
{
  const int e = blockIdx.x;
  const int lane = threadIdx.x;
  const uint64_t below = (1ull << lane) - 1ull;
  int total = 0;
  for (int s0 = 0; s0 < S_SLOTS; s0 += 256) {
#pragma unroll
    for (int jj = 0; jj < 4; ++jj) {
      int s = s0 + jj * 64 + lane;
      bool m = (slot_eid[s] == e);
      uint64_t bal = __ballot(m);
      if (m) {
        int rank = total + __popcll(bal & below);
        if (rank < CAP) {
          slot2buf[s] = e * CAP + rank;
          row_token[e * CAP + rank] = s >> 1;   // source token
        } else {
          slot2buf[s] = -1;                     // capacity-dropped
        }
      }
      total += __popcll(bal);
    }
  }
}

// ---------------------------------------------------------------------------
// Kernel 4: grouped expert GEMM, bf16 MFMA 16x16x32, 128x128 tile, BK=32,
// m97 structure with width-16 global_load_lds; A rows gathered via token ids.
// Grid: 64 experts * 20 m-tiles * 2 n-tiles = 2560 blocks.
// ---------------------------------------------------------------------------
__global__ __launch_bounds__(256) void gemm_kernel(
    const u16* __restrict__ x_bf16, const u16* __restrict__ WT,
    const int* __restrict__ row_token, u16* __restrict__ y)
{
  __shared__ u16 A_s[128 * 32];
  __shared__ u16 B_s[128 * 32];
  __shared__ int tok_s[128];

  const int b = blockIdx.x;
  const int e = b / 40;
  const int r = b % 40;
  const int m0 = (r >> 1) * 128, n0 = (r & 1) * 128;
  const int t = threadIdx.x;

  if (t < 128) tok_s[t] = row_token[e * CAP + m0 + t];
  __syncthreads();

  const int w = t >> 6, lane = t & 63;
  const int rsub = lane >> 2;          // 0..15: row within a 16-row stage call
  const int koff = (lane & 3) * 8;     // bf16 elems within the 32-wide k chunk

  const int ra0 = w * 32 + rsub;
  const int ra1 = ra0 + 16;
  const char* pa0 = (const char*)(x_bf16 + (size_t)tok_s[ra0] * 256 + koff);
  const char* pa1 = (const char*)(x_bf16 + (size_t)tok_s[ra1] * 256 + koff);
  const u16* WTe = WT + (size_t)e * 65536;
  const char* pb0 = (const char*)(WTe + (size_t)(n0 + ra0) * 256 + koff);
  const char* pb1 = (const char*)(WTe + (size_t)(n0 + ra1) * 256 + koff);

  char* ldsA0 = (char*)A_s + (w * 32) * 64;        // wave-uniform bases
  char* ldsA1 = (char*)A_s + (w * 32 + 16) * 64;
  char* ldsB0 = (char*)B_s + (w * 32) * 64;
  char* ldsB1 = (char*)B_s + (w * 32 + 16) * 64;

  const int wm = w & 1, wn = w >> 1;
  const int lr = lane & 15, q = lane >> 4;

  f32x4 acc[4][4];
#pragma unroll
  for (int mt = 0; mt < 4; ++mt)
#pragma unroll
    for (int nt = 0; nt < 4; ++nt) acc[mt][nt] = (f32x4){0.f, 0.f, 0.f, 0.f};

  for (int kt = 0; kt < 8; ++kt) {
    gload16(pa0, ldsA0);
    gload16(pa1, ldsA1);
    gload16(pb0, ldsB0);
    gload16(pb1, ldsB1);
    __syncthreads();                    // drains vmcnt before frag reads
    bf16x8 af[4], bg[4];
#pragma unroll
    for (int mt = 0; mt < 4; ++mt)
      af[mt] = *(const bf16x8*)&A_s[(wm * 64 + mt * 16 + lr) * 32 + q * 8];
#pragma unroll
    for (int nt = 0; nt < 4; ++nt)
      bg[nt] = *(const bf16x8*)&B_s[(wn * 64 + nt * 16 + lr) * 32 + q * 8];
#pragma unroll
    for (int mt = 0; mt < 4; ++mt)
#pragma unroll
      for (int nt = 0; nt < 4; ++nt)
        acc[mt][nt] = __builtin_amdgcn_mfma_f32_16x16x32_bf16(
            af[mt], bg[nt], acc[mt][nt], 0, 0, 0);
    __syncthreads();                    // all waves done reading before restage
    pa0 += 64; pa1 += 64; pb0 += 64; pb1 += 64;   // advance 32 bf16 in k
  }

  // C/D layout: col=lane&15, row=quad*4+reg  [verified m89/m91]
  u16* ye = y + (size_t)e * CAP * 256;
#pragma unroll
  for (int mt = 0; mt < 4; ++mt) {
    int grow = m0 + wm * 64 + mt * 16 + q * 4;
#pragma unroll
    for (int nt = 0; nt < 4; ++nt) {
      int gcol = n0 + wn * 64 + nt * 16 + lr;
#pragma unroll
      for (int rr = 0; rr < 4; ++rr)
        ye[(size_t)(grow + rr) * 256 + gcol] = f2bf(acc[mt][nt][rr]);
    }
  }
}

// ---------------------------------------------------------------------------
// Kernel 5: combine. out[t] = s0*y[p0] + s1*y[p1] (dropped -> 0). Wave/token.
// ---------------------------------------------------------------------------
__global__ __launch_bounds__(256) void combine_kernel(
    const u16* __restrict__ y, const int* __restrict__ slot2buf,
    const float* __restrict__ slot_score, float* __restrict__ out)
{
  const int tok  = blockIdx.x * 4 + (threadIdx.x >> 6);
  const int lane = threadIdx.x & 63;
  const int   p0 = slot2buf[2 * tok],   p1 = slot2buf[2 * tok + 1];
  const float s0 = slot_score[2 * tok], s1 = slot_score[2 * tok + 1];
  float o0 = 0.f, o1 = 0.f, o2 = 0.f, o3 = 0.f;
  if (p0 >= 0) {
    u16x4 h = *(const u16x4*)&y[(size_t)p0 * 256 + lane * 4];
    o0 = fmaf(s0, bf2f(h.x), o0); o1 = fmaf(s0, bf2f(h.y), o1);
    o2 = fmaf(s0, bf2f(h.z), o2); o3 = fmaf(s0, bf2f(h.w), o3);
  }
  if (p1 >= 0) {
    u16x4 h = *(const u16x4*)&y[(size_t)p1 * 256 + lane * 4];
    o0 = fmaf(s1, bf2f(h.x), o0); o1 = fmaf(s1, bf2f(h.y), o1);
    o2 = fmaf(s1, bf2f(h.z), o2); o3 = fmaf(s1, bf2f(h.w), o3);
  }
  fvec4 o = {o0, o1, o2, o3};
  *(fvec4*)&out[(size_t)tok * 256 + lane * 4] = o;
}

// ---------------------------------------------------------------------------
// Kernel 6: aux loss = mean((load/N - 1/E)^2). One wave.
// ---------------------------------------------------------------------------
__global__ __launch_bounds__(64) void aux_kernel(
    const float* __restrict__ load_g, float* __restrict__ out_aux)
{
  const int lane = threadIdx.x;
  float l = load_g[lane] * (1.0f / 65536.0f) - (1.0f / 64.0f);
  float v = l * l;
#pragma unroll
  for (int off = 1; off < 64; off <<= 1) v += __shfl_xor(v, off);
  if (lane == 0) out_aux[0] = v * (1.0f / 64.0f);
}

// ---------------------------------------------------------------------------
// Workspace layout (bytes):
//   0        slot_score f32[131072]   (512K)
//   524288   slot_eid   i32[131072]   (512K)
//   1048576  slot2buf   i32[131072]   (512K)
//   1572864  row_token  i32[163840]   (640K)  -- memset 0 each call
//   2228224  load_g     f32[64]               -- memset 0 each call
//   4194304  x_bf16     u16[16777216] (32M)
//   37748736 WT         u16[4194304]  (8M)
//   46137344 y          u16[41943040] (80M)
// total ~124 MB
// ---------------------------------------------------------------------------
extern "C" void kernel_launch(void* const* d_in, const int* in_sizes, int n_in,
                              void* d_out, int out_size, void* d_ws, size_t ws_size,
                              hipStream_t stream)
{
  const float* x  = (const float*)d_in[0];
  const float* Wg = (const float*)d_in[1];
  const float* We = (const float*)d_in[2];
  float* out = (float*)d_out;

  char* ws = (char*)d_ws;
  float* slot_score = (float*)(ws + 0);
  int*   slot_eid   = (int*)(ws + 524288);
  int*   slot2buf   = (int*)(ws + 1048576);
  int*   row_token  = (int*)(ws + 1572864);
  float* load_g     = (float*)(ws + 2228224);
  u16*   x_bf16     = (u16*)(ws + 4194304);
  u16*   WT         = (u16*)(ws + 37748736);
  u16*   y          = (u16*)(ws + 46137344);

  hipMemsetAsync(row_token, 0, 655360, stream);   // unfilled rows -> token 0
  hipMemsetAsync(load_g, 0, 256, stream);

  gating_kernel<<<1024, 256, 0, stream>>>(x, Wg, x_bf16, slot_score, slot_eid, load_g);
  wtrans_kernel<<<1024, 256, 0, stream>>>(We, WT);
  compact_kernel<<<64, 64, 0, stream>>>(slot_eid, slot2buf, row_token);
  gemm_kernel<<<2560, 256, 0, stream>>>(x_bf16, WT, row_token, y);
  combine_kernel<<<16384, 256, 0, stream>>>(y, slot2buf, slot_score, out);
  aux_kernel<<<1, 64, 0, stream>>>(load_g, out + 16777216);
}

// Round 2
// 283.734 us; speedup vs baseline: 2.7763x; 2.7763x over previous
//
#include <hip/hip_runtime.h>
#include <stdint.h>

// Problem constants (B=8,T=8192,C=256,E=64, top-2, cap_factor=1.25)
#define N_TOK   65536
#define S_SLOTS 131072
#define NEXP    64
#define CDIM    256
#define CAP     2560          // int(1.25 * 131072 / 64)
#define NCHUNK  1024          // 128 slots per chunk (= one gating block)

typedef unsigned short u16;
typedef float    fvec4  __attribute__((ext_vector_type(4)));
typedef float    f32x4  __attribute__((ext_vector_type(4)));
typedef __bf16   bf16x8 __attribute__((ext_vector_type(8)));
typedef unsigned short u16x4 __attribute__((ext_vector_type(4)));

typedef __attribute__((address_space(1))) const void gvoid_t;
typedef __attribute__((address_space(3))) void       svoid_t;

__device__ __forceinline__ u16 f2bf(float f) {          // RNE float->bf16
  uint32_t u = __builtin_bit_cast(uint32_t, f);
  u += 0x7fffu + ((u >> 16) & 1u);
  return (u16)(u >> 16);
}
__device__ __forceinline__ float bf2f(u16 h) {
  return __builtin_bit_cast(float, (uint32_t)h << 16);
}
__device__ __forceinline__ void gload16(const void* g, void* l) {
  __builtin_amdgcn_global_load_lds(
      reinterpret_cast<gvoid_t*>(reinterpret_cast<uintptr_t>(g)),
      reinterpret_cast<svoid_t*>(reinterpret_cast<uintptr_t>(l)),
      16, 0, 0);
}

// ---------------------------------------------------------------------------
// Kernel 1: gating. fp32 GEMM (64 tok x 64 exp, K=256) + softmax + top2 +
// x->bf16 conversion + load partials + per-chunk expert histogram.
// Block=256 thr, 64 tokens/block => this block IS slot-chunk blockIdx.x
// (slots b*128 .. b*128+127).
// ---------------------------------------------------------------------------
__global__ __launch_bounds__(256) void gating_kernel(
    const float* __restrict__ x, const float* __restrict__ Wg,
    u16* __restrict__ x_bf16, float* __restrict__ slot_score,
    int* __restrict__ slot_eid, float* __restrict__ load_g,
    int* __restrict__ chunk_hist)
{
  __shared__ float W_s[64 * 64];    // [kk][e]
  __shared__ float A_s[64 * 68];    // [m][kk] pad->68
  __shared__ float L_s[64 * 65];    // logits [m][e]
  __shared__ float loadp[4 * 64];
  __shared__ int   hist_s[64];

  const int t  = threadIdx.x;
  const int m0 = blockIdx.x * 64;
  const int ty = t >> 4, tx = t & 15;

  if (t < 64) hist_s[t] = 0;

  float acc[4][4];
#pragma unroll
  for (int j = 0; j < 4; ++j)
#pragma unroll
    for (int i = 0; i < 4; ++i) acc[j][i] = 0.f;

  for (int kt = 0; kt < 4; ++kt) {
    const int k0 = kt * 64;
#pragma unroll
    for (int p = 0; p < 4; ++p) {     // stage W tile [64k][64e]
      int idx = p * 1024 + t * 4;
      int kk = idx >> 6, e = idx & 63;
      *(fvec4*)&W_s[kk * 64 + e] = *(const fvec4*)&Wg[(size_t)(k0 + kk) * 64 + e];
    }
#pragma unroll
    for (int p = 0; p < 4; ++p) {     // stage A tile [64m][64k] + write x_bf16
      int idx = p * 1024 + t * 4;
      int m = idx >> 6, k = idx & 63;
      fvec4 v = *(const fvec4*)&x[(size_t)(m0 + m) * 256 + k0 + k];
      *(fvec4*)&A_s[m * 68 + k] = v;
      u16x4 h;
      h.x = f2bf(v.x); h.y = f2bf(v.y); h.z = f2bf(v.z); h.w = f2bf(v.w);
      *(u16x4*)&x_bf16[(size_t)(m0 + m) * 256 + k0 + k] = h;
    }
    __syncthreads();
#pragma unroll
    for (int k4 = 0; k4 < 16; ++k4) {
      fvec4 av[4], bv[4];
#pragma unroll
      for (int j = 0; j < 4; ++j)
        av[j] = *(const fvec4*)&A_s[(ty * 4 + j) * 68 + k4 * 4];
#pragma unroll
      for (int kk = 0; kk < 4; ++kk)
        bv[kk] = *(const fvec4*)&W_s[(k4 * 4 + kk) * 64 + tx * 4];
#pragma unroll
      for (int j = 0; j < 4; ++j)
#pragma unroll
        for (int i = 0; i < 4; ++i) {
          acc[j][i] = fmaf(av[j][0], bv[0][i], acc[j][i]);
          acc[j][i] = fmaf(av[j][1], bv[1][i], acc[j][i]);
          acc[j][i] = fmaf(av[j][2], bv[2][i], acc[j][i]);
          acc[j][i] = fmaf(av[j][3], bv[3][i], acc[j][i]);
        }
    }
    __syncthreads();
  }

#pragma unroll
  for (int j = 0; j < 4; ++j)
#pragma unroll
    for (int i = 0; i < 4; ++i)
      L_s[(ty * 4 + j) * 65 + tx * 4 + i] = acc[j][i];
  __syncthreads();

  const int wave = t >> 6, lane = t & 63;
  float lsum = 0.f;
  for (int it = 0; it < 16; ++it) {
    int tl = wave * 16 + it;
    float lg = L_s[tl * 65 + lane];
    float mx = lg;
#pragma unroll
    for (int off = 1; off < 64; off <<= 1) mx = fmaxf(mx, __shfl_xor(mx, off));
    float pe = expf(lg - mx);
    float sm = pe;
#pragma unroll
    for (int off = 1; off < 64; off <<= 1) sm += __shfl_xor(sm, off);
    float p = pe / sm;                 // gate prob (no renorm, matches ref)
    lsum += p;
    // top-1: max value, lowest index on ties (matches lax.top_k)
    float v1 = p; int i1 = lane;
#pragma unroll
    for (int off = 1; off < 64; off <<= 1) {
      float vo = __shfl_xor(v1, off); int io = __shfl_xor(i1, off);
      if (vo > v1 || (vo == v1 && io < i1)) { v1 = vo; i1 = io; }
    }
    float pm = (lane == i1) ? -1.f : p;
    float v2 = pm; int i2 = lane;
#pragma unroll
    for (int off = 1; off < 64; off <<= 1) {
      float vo = __shfl_xor(v2, off); int io = __shfl_xor(i2, off);
      if (vo > v2 || (vo == v2 && io < i2)) { v2 = vo; i2 = io; }
    }
    if (lane == 0) {
      int tg = m0 + tl;
      slot_eid[2 * tg]     = i1;
      slot_eid[2 * tg + 1] = i2;
      slot_score[2 * tg]     = v1;
      slot_score[2 * tg + 1] = v2;
      atomicAdd(&hist_s[i1], 1);
      atomicAdd(&hist_s[i2], 1);
    }
  }
  loadp[wave * 64 + lane] = lsum;
  __syncthreads();
  if (t < 64) {
    float s = loadp[t] + loadp[64 + t] + loadp[128 + t] + loadp[192 + t];
    atomicAdd(&load_g[t], s);
    chunk_hist[blockIdx.x * 64 + t] = hist_s[t];
  }
}

// ---------------------------------------------------------------------------
// Kernel 2: W_experts [e][k][d] fp32 -> WT [e][d][k] bf16 (K-fast for MFMA B).
// ---------------------------------------------------------------------------
__global__ __launch_bounds__(256) void wtrans_kernel(
    const float* __restrict__ W, u16* __restrict__ WT)
{
  __shared__ float tile[64 * 65];
  const int b = blockIdx.x;
  const int e = b >> 4, tt = b & 15;
  const int k0 = (tt >> 2) * 64, d0 = (tt & 3) * 64;
  const int t = threadIdx.x;
  const int j = t & 63, i0 = t >> 6;
  const float* We = W + (size_t)e * 65536;
#pragma unroll
  for (int p = 0; p < 16; ++p) {
    int i = p * 4 + i0;
    tile[i * 65 + j] = We[(size_t)(k0 + i) * 256 + d0 + j];   // coalesced on d
  }
  __syncthreads();
  u16* WTe = WT + (size_t)e * 65536;
#pragma unroll
  for (int p = 0; p < 16; ++p) {
    int d = p * 4 + i0;
    WTe[(size_t)(d0 + d) * 256 + k0 + j] = f2bf(tile[j * 65 + d]); // coalesced on k
  }
}

// ---------------------------------------------------------------------------
// Kernel 3a: per-expert exclusive scan over the 1024 chunk histograms.
// 64 blocks (one per expert) x 256 threads, 4 chunks/thread; in-place.
// ---------------------------------------------------------------------------
__global__ __launch_bounds__(256) void scan_kernel(int* __restrict__ hist)
{
  const int e = blockIdx.x;
  const int t = threadIdx.x;
  const int lane = t & 63, w = t >> 6;
  int h[4];
#pragma unroll
  for (int i = 0; i < 4; ++i) h[i] = hist[(t * 4 + i) * 64 + e];
  int local = h[0] + h[1] + h[2] + h[3];
  int v = local;                         // inclusive wave scan
#pragma unroll
  for (int off = 1; off < 64; off <<= 1) {
    int u = __shfl_up(v, off);
    if (lane >= off) v += u;
  }
  __shared__ int wtot[4];
  if (lane == 63) wtot[w] = v;
  __syncthreads();
  int woff = 0;
  for (int i = 0; i < w; ++i) woff += wtot[i];
  int excl = woff + v - local;
  hist[(t * 4 + 0) * 64 + e] = excl;
  hist[(t * 4 + 1) * 64 + e] = excl + h[0];
  hist[(t * 4 + 2) * 64 + e] = excl + h[0] + h[1];
  hist[(t * 4 + 3) * 64 + e] = excl + h[0] + h[1] + h[2];
}

// ---------------------------------------------------------------------------
// Kernel 3b: rank. 1024 blocks x 128 thr (one slot each). Stable FIFO rank =
// chunk_base[e] + cross-wave offset + within-wave prior-match count.
// Bit-identical semantics to the reference cumsum rank.
// ---------------------------------------------------------------------------
__global__ __launch_bounds__(128) void rank_kernel(
    const int* __restrict__ slot_eid, const int* __restrict__ base,
    int* __restrict__ slot2buf, int* __restrict__ row_token)
{
  const int c = blockIdx.x;
  const int t = threadIdx.x;
  const int s = c * 128 + t;
  const int lane = t & 63, w = t >> 6;
  const int e = slot_eid[s];
  __shared__ int hist0[64];
  if (t < 64) hist0[t] = 0;
  __syncthreads();
  int rank = 0, cnt = 0;
#pragma unroll
  for (int k = 0; k < 64; ++k) {
    int eo = __shfl(e, k);
    bool m = (eo == e);
    rank += (m && k < lane) ? 1 : 0;
    cnt  += m ? 1 : 0;
  }
  if (w == 0 && rank == cnt - 1) hist0[e] = cnt;   // last lane of its expert
  __syncthreads();
  int g = base[c * 64 + e] + rank + (w ? hist0[e] : 0);
  if (g < CAP) {
    slot2buf[s] = e * CAP + g;
    row_token[e * CAP + g] = s >> 1;
  } else {
    slot2buf[s] = -1;                               // capacity-dropped
  }
}

// ---------------------------------------------------------------------------
// Kernel 4: grouped expert GEMM, bf16 MFMA 16x16x32, 128x128 tile, BK=32,
// m97 structure with width-16 global_load_lds; A rows gathered via token ids.
// ---------------------------------------------------------------------------
__global__ __launch_bounds__(256) void gemm_kernel(
    const u16* __restrict__ x_bf16, const u16* __restrict__ WT,
    const int* __restrict__ row_token, u16* __restrict__ y)
{
  __shared__ u16 A_s[128 * 32];
  __shared__ u16 B_s[128 * 32];
  __shared__ int tok_s[128];

  const int b = blockIdx.x;
  const int e = b / 40;
  const int r = b % 40;
  const int m0 = (r >> 1) * 128, n0 = (r & 1) * 128;
  const int t = threadIdx.x;

  if (t < 128) tok_s[t] = row_token[e * CAP + m0 + t];
  __syncthreads();

  const int w = t >> 6, lane = t & 63;
  const int rsub = lane >> 2;
  const int koff = (lane & 3) * 8;

  const int ra0 = w * 32 + rsub;
  const int ra1 = ra0 + 16;
  const char* pa0 = (const char*)(x_bf16 + (size_t)tok_s[ra0] * 256 + koff);
  const char* pa1 = (const char*)(x_bf16 + (size_t)tok_s[ra1] * 256 + koff);
  const u16* WTe = WT + (size_t)e * 65536;
  const char* pb0 = (const char*)(WTe + (size_t)(n0 + ra0) * 256 + koff);
  const char* pb1 = (const char*)(WTe + (size_t)(n0 + ra1) * 256 + koff);

  char* ldsA0 = (char*)A_s + (w * 32) * 64;
  char* ldsA1 = (char*)A_s + (w * 32 + 16) * 64;
  char* ldsB0 = (char*)B_s + (w * 32) * 64;
  char* ldsB1 = (char*)B_s + (w * 32 + 16) * 64;

  const int wm = w & 1, wn = w >> 1;
  const int lr = lane & 15, q = lane >> 4;

  f32x4 acc[4][4];
#pragma unroll
  for (int mt = 0; mt < 4; ++mt)
#pragma unroll
    for (int nt = 0; nt < 4; ++nt) acc[mt][nt] = (f32x4){0.f, 0.f, 0.f, 0.f};

  for (int kt = 0; kt < 8; ++kt) {
    gload16(pa0, ldsA0);
    gload16(pa1, ldsA1);
    gload16(pb0, ldsB0);
    gload16(pb1, ldsB1);
    __syncthreads();
    bf16x8 af[4], bg[4];
#pragma unroll
    for (int mt = 0; mt < 4; ++mt)
      af[mt] = *(const bf16x8*)&A_s[(wm * 64 + mt * 16 + lr) * 32 + q * 8];
#pragma unroll
    for (int nt = 0; nt < 4; ++nt)
      bg[nt] = *(const bf16x8*)&B_s[(wn * 64 + nt * 16 + lr) * 32 + q * 8];
#pragma unroll
    for (int mt = 0; mt < 4; ++mt)
#pragma unroll
      for (int nt = 0; nt < 4; ++nt)
        acc[mt][nt] = __builtin_amdgcn_mfma_f32_16x16x32_bf16(
            af[mt], bg[nt], acc[mt][nt], 0, 0, 0);
    __syncthreads();
    pa0 += 64; pa1 += 64; pb0 += 64; pb1 += 64;
  }

  // C/D layout: col=lane&15, row=quad*4+reg  [verified m89/m91]
  u16* ye = y + (size_t)e * CAP * 256;
#pragma unroll
  for (int mt = 0; mt < 4; ++mt) {
    int grow = m0 + wm * 64 + mt * 16 + q * 4;
#pragma unroll
    for (int nt = 0; nt < 4; ++nt) {
      int gcol = n0 + wn * 64 + nt * 16 + lr;
#pragma unroll
      for (int rr = 0; rr < 4; ++rr)
        ye[(size_t)(grow + rr) * 256 + gcol] = f2bf(acc[mt][nt][rr]);
    }
  }
}

// ---------------------------------------------------------------------------
// Kernel 5: combine. out[t] = s0*y[p0] + s1*y[p1] (dropped -> 0). Wave/token.
// ---------------------------------------------------------------------------
__global__ __launch_bounds__(256) void combine_kernel(
    const u16* __restrict__ y, const int* __restrict__ slot2buf,
    const float* __restrict__ slot_score, float* __restrict__ out)
{
  const int tok  = blockIdx.x * 4 + (threadIdx.x >> 6);
  const int lane = threadIdx.x & 63;
  const int   p0 = slot2buf[2 * tok],   p1 = slot2buf[2 * tok + 1];
  const float s0 = slot_score[2 * tok], s1 = slot_score[2 * tok + 1];
  float o0 = 0.f, o1 = 0.f, o2 = 0.f, o3 = 0.f;
  if (p0 >= 0) {
    u16x4 h = *(const u16x4*)&y[(size_t)p0 * 256 + lane * 4];
    o0 = fmaf(s0, bf2f(h.x), o0); o1 = fmaf(s0, bf2f(h.y), o1);
    o2 = fmaf(s0, bf2f(h.z), o2); o3 = fmaf(s0, bf2f(h.w), o3);
  }
  if (p1 >= 0) {
    u16x4 h = *(const u16x4*)&y[(size_t)p1 * 256 + lane * 4];
    o0 = fmaf(s1, bf2f(h.x), o0); o1 = fmaf(s1, bf2f(h.y), o1);
    o2 = fmaf(s1, bf2f(h.z), o2); o3 = fmaf(s1, bf2f(h.w), o3);
  }
  fvec4 o = {o0, o1, o2, o3};
  *(fvec4*)&out[(size_t)tok * 256 + lane * 4] = o;
}

// ---------------------------------------------------------------------------
// Kernel 6: aux loss = mean((load/N - 1/E)^2). One wave.
// ---------------------------------------------------------------------------
__global__ __launch_bounds__(64) void aux_kernel(
    const float* __restrict__ load_g, float* __restrict__ out_aux)
{
  const int lane = threadIdx.x;
  float l = load_g[lane] * (1.0f / 65536.0f) - (1.0f / 64.0f);
  float v = l * l;
#pragma unroll
  for (int off = 1; off < 64; off <<= 1) v += __shfl_xor(v, off);
  if (lane == 0) out_aux[0] = v * (1.0f / 64.0f);
}

// ---------------------------------------------------------------------------
// Workspace layout (bytes):
//   0        slot_score f32[131072]   (512K)
//   524288   slot_eid   i32[131072]   (512K)
//   1048576  slot2buf   i32[131072]   (512K)
//   1572864  row_token  i32[163840]   (640K)  -- memset 0 each call
//   2228224  load_g     f32[64]               -- memset 0 each call
//   2359296  chunk_hist i32[1024*64]  (256K)  -- fully written by gating
//   4194304  x_bf16     u16[16777216] (32M)
//   37748736 WT         u16[4194304]  (8M)
//   46137344 y          u16[41943040] (80M)
// total ~124 MB
// ---------------------------------------------------------------------------
extern "C" void kernel_launch(void* const* d_in, const int* in_sizes, int n_in,
                              void* d_out, int out_size, void* d_ws, size_t ws_size,
                              hipStream_t stream)
{
  const float* x  = (const float*)d_in[0];
  const float* Wg = (const float*)d_in[1];
  const float* We = (const float*)d_in[2];
  float* out = (float*)d_out;

  char* ws = (char*)d_ws;
  float* slot_score = (float*)(ws + 0);
  int*   slot_eid   = (int*)(ws + 524288);
  int*   slot2buf   = (int*)(ws + 1048576);
  int*   row_token  = (int*)(ws + 1572864);
  float* load_g     = (float*)(ws + 2228224);
  int*   chunk_hist = (int*)(ws + 2359296);
  u16*   x_bf16     = (u16*)(ws + 4194304);
  u16*   WT         = (u16*)(ws + 37748736);
  u16*   y          = (u16*)(ws + 46137344);

  hipMemsetAsync(row_token, 0, 655360, stream);   // unfilled rows -> token 0
  hipMemsetAsync(load_g, 0, 256, stream);

  gating_kernel<<<1024, 256, 0, stream>>>(x, Wg, x_bf16, slot_score, slot_eid,
                                          load_g, chunk_hist);
  wtrans_kernel<<<1024, 256, 0, stream>>>(We, WT);
  scan_kernel<<<64, 256, 0, stream>>>(chunk_hist);
  rank_kernel<<<1024, 128, 0, stream>>>(slot_eid, chunk_hist, slot2buf, row_token);
  gemm_kernel<<<2560, 256, 0, stream>>>(x_bf16, WT, row_token, y);
  combine_kernel<<<16384, 256, 0, stream>>>(y, slot2buf, slot_score, out);
  aux_kernel<<<1, 64, 0, stream>>>(load_g, out + 16777216);
}

// Round 3
// 238.976 us; speedup vs baseline: 3.2963x; 1.1873x over previous
//
#include <hip/hip_runtime.h>
#include <stdint.h>

// Problem constants (B=8,T=8192,C=256,E=64, top-2, cap_factor=1.25)
#define N_TOK   65536
#define S_SLOTS 131072
#define NEXP    64
#define CDIM    256
#define CAP     2560          // int(1.25 * 131072 / 64)
#define NCHUNK  1024          // 128 slots per chunk (= one gating block)

typedef unsigned short u16;
typedef float    fvec4  __attribute__((ext_vector_type(4)));
typedef float    f32x4  __attribute__((ext_vector_type(4)));
typedef __bf16   bf16x8 __attribute__((ext_vector_type(8)));
typedef unsigned short u16x4 __attribute__((ext_vector_type(4)));

typedef __attribute__((address_space(1))) const void gvoid_t;
typedef __attribute__((address_space(3))) void       svoid_t;

__device__ __forceinline__ u16 f2bf(float f) {          // RNE float->bf16
  uint32_t u = __builtin_bit_cast(uint32_t, f);
  u += 0x7fffu + ((u >> 16) & 1u);
  return (u16)(u >> 16);
}
__device__ __forceinline__ float bf2f(u16 h) {
  return __builtin_bit_cast(float, (uint32_t)h << 16);
}
__device__ __forceinline__ void gload16(const void* g, void* l) {
  __builtin_amdgcn_global_load_lds(
      reinterpret_cast<gvoid_t*>(reinterpret_cast<uintptr_t>(g)),
      reinterpret_cast<svoid_t*>(reinterpret_cast<uintptr_t>(l)),
      16, 0, 0);
}

// ---------------------------------------------------------------------------
// Kernel 1: gating. fp32 GEMM (64 tok x 64 exp, K=256) + softmax + top2 +
// x->bf16 conversion + load partials + per-chunk expert histogram.
// Tail is lane=token serial (NO cross-lane ops); LDS tail region aliases the
// GEMM staging region (34 KB total -> 4 blocks/CU).
// ---------------------------------------------------------------------------
__global__ __launch_bounds__(256) void gating_kernel(
    const float* __restrict__ x, const float* __restrict__ Wg,
    u16* __restrict__ x_bf16, float* __restrict__ slot_score,
    int* __restrict__ slot_eid, float* __restrict__ load_g,
    int* __restrict__ chunk_hist)
{
  __shared__ float smem[8448];       // GEMM: W_s[4096] + A_s[64*68]
  __shared__ int   hist_s[64];       // tail aliases smem (see offsets below)
  float* W_s   = smem;               // [k][e] 64x64
  float* A_s   = smem + 4096;        // [m][k] pitch 68
  float* L_s   = smem;               // [m][e] pitch 65  (tail phase, <=4160)
  float* PMAXs = smem + 4160;        // [w][tok] 4x64
  float* PV1   = smem + 4416;
  int*   PI1   = (int*)(smem + 4672);
  float* PV2   = smem + 4928;
  int*   PI2   = (int*)(smem + 5184);
  float* PSUM  = smem + 5440;
  float* RINVs = smem + 5696;        // [64]
  float* PLOAD = smem + 5760;        // [256]

  const int t  = threadIdx.x;
  const int m0 = blockIdx.x * 64;
  const int ty = t >> 4, tx = t & 15;

  if (t < 64) hist_s[t] = 0;

  float acc[4][4];
#pragma unroll
  for (int j = 0; j < 4; ++j)
#pragma unroll
    for (int i = 0; i < 4; ++i) acc[j][i] = 0.f;

  for (int kt = 0; kt < 4; ++kt) {
    const int k0 = kt * 64;
#pragma unroll
    for (int p = 0; p < 4; ++p) {     // stage W tile [64k][64e]
      int idx = p * 1024 + t * 4;
      int kk = idx >> 6, e = idx & 63;
      *(fvec4*)&W_s[kk * 64 + e] = *(const fvec4*)&Wg[(size_t)(k0 + kk) * 64 + e];
    }
#pragma unroll
    for (int p = 0; p < 4; ++p) {     // stage A tile [64m][64k] + write x_bf16
      int idx = p * 1024 + t * 4;
      int m = idx >> 6, k = idx & 63;
      fvec4 v = *(const fvec4*)&x[(size_t)(m0 + m) * 256 + k0 + k];
      *(fvec4*)&A_s[m * 68 + k] = v;
      u16x4 h;
      h.x = f2bf(v.x); h.y = f2bf(v.y); h.z = f2bf(v.z); h.w = f2bf(v.w);
      *(u16x4*)&x_bf16[(size_t)(m0 + m) * 256 + k0 + k] = h;
    }
    __syncthreads();
#pragma unroll
    for (int k4 = 0; k4 < 16; ++k4) {
      fvec4 av[4], bv[4];
#pragma unroll
      for (int j = 0; j < 4; ++j)
        av[j] = *(const fvec4*)&A_s[(ty * 4 + j) * 68 + k4 * 4];
#pragma unroll
      for (int kk = 0; kk < 4; ++kk)
        bv[kk] = *(const fvec4*)&W_s[(k4 * 4 + kk) * 64 + tx * 4];
#pragma unroll
      for (int j = 0; j < 4; ++j)
#pragma unroll
        for (int i = 0; i < 4; ++i) {
          acc[j][i] = fmaf(av[j][0], bv[0][i], acc[j][i]);
          acc[j][i] = fmaf(av[j][1], bv[1][i], acc[j][i]);
          acc[j][i] = fmaf(av[j][2], bv[2][i], acc[j][i]);
          acc[j][i] = fmaf(av[j][3], bv[3][i], acc[j][i]);
        }
    }
    __syncthreads();                  // also guards L_s alias overwrite below
  }

  // logits -> LDS (pitch 65: column access is bank-conflict-free)
#pragma unroll
  for (int j = 0; j < 4; ++j)
#pragma unroll
    for (int i = 0; i < 4; ++i)
      L_s[(ty * 4 + j) * 65 + tx * 4 + i] = acc[j][i];
  __syncthreads();

  const int w = t >> 6, lane = t & 63;

  // pass1: per-wave partial max + top-2 (on logits; softmax is monotone).
  // Ascending expert order + strict '>' == lowest-index-on-tie (lax.top_k).
  float pm = -3.4e38f, a1 = -3.4e38f, a2 = -3.4e38f;
  int   j1 = 0, j2 = 0;
#pragma unroll
  for (int ii = 0; ii < 16; ++ii) {
    int e = w * 16 + ii;
    float lg = L_s[lane * 65 + e];
    pm = fmaxf(pm, lg);
    if (lg > a1)      { a2 = a1; j2 = j1; a1 = lg; j1 = e; }
    else if (lg > a2) { a2 = lg; j2 = e; }
  }
  PMAXs[w * 64 + lane] = pm;
  PV1[w * 64 + lane] = a1; PI1[w * 64 + lane] = j1;
  PV2[w * 64 + lane] = a2; PI2[w * 64 + lane] = j2;
  __syncthreads();

  // merge the 4 sorted pairs (redundantly in every wave; each needs the max).
  // Current pair always holds LOWER expert indices than the incoming range,
  // so strict '>' on the incoming keeps lowest-index on ties.
  float m  = PMAXs[lane];
  float v1 = PV1[lane]; int i1 = PI1[lane];
  float v2 = PV2[lane]; int i2 = PI2[lane];
#pragma unroll
  for (int ww = 1; ww < 4; ++ww) {
    m = fmaxf(m, PMAXs[ww * 64 + lane]);
    float b1 = PV1[ww * 64 + lane]; int bi1 = PI1[ww * 64 + lane];
    float b2 = PV2[ww * 64 + lane]; int bi2 = PI2[ww * 64 + lane];
    if (b1 > v1) {
      if (v1 >= b2) { v2 = v1; i2 = i1; } else { v2 = b2; i2 = bi2; }
      v1 = b1; i1 = bi1;
    } else if (b1 > v2) { v2 = b1; i2 = bi1; }
  }

  // pass2: E = exp(lg - max) in place (per-wave disjoint columns) + row partial
  float s = 0.f;
#pragma unroll
  for (int ii = 0; ii < 16; ++ii) {
    int e = w * 16 + ii;
    float E = __expf(L_s[lane * 65 + e] - m);
    L_s[lane * 65 + e] = E;
    s += E;
  }
  PSUM[w * 64 + lane] = s;
  __syncthreads();

  if (w == 0) {                       // finalize: scores, ids, chunk histogram
    float rs = PSUM[lane] + PSUM[64 + lane] + PSUM[128 + lane] + PSUM[192 + lane];
    float ri = 1.0f / rs;
    RINVs[lane] = ri;
    float sc1 = L_s[lane * 65 + i1] * ri;
    float sc2 = L_s[lane * 65 + i2] * ri;
    int tg = m0 + lane;
    slot_eid[2 * tg]     = i1;
    slot_eid[2 * tg + 1] = i2;
    slot_score[2 * tg]     = sc1;
    slot_score[2 * tg + 1] = sc2;
    atomicAdd(&hist_s[i1], 1);
    atomicAdd(&hist_s[i2], 1);
  }
  __syncthreads();

  // load partials: thread t covers expert=lane, tokens [w*16, w*16+16)
  {
    float sl = 0.f;
#pragma unroll
    for (int jj = 0; jj < 16; ++jj) {
      int j = w * 16 + jj;
      sl = fmaf(L_s[j * 65 + lane], RINVs[j], sl);
    }
    PLOAD[t] = sl;
  }
  __syncthreads();
  if (t < 64) {
    float sl = PLOAD[t] + PLOAD[64 + t] + PLOAD[128 + t] + PLOAD[192 + t];
    atomicAdd(&load_g[t], sl);
    chunk_hist[blockIdx.x * 64 + t] = hist_s[t];
  }
}

// ---------------------------------------------------------------------------
// Kernel 2: W_experts [e][k][d] fp32 -> WT [e][d][k] bf16 (K-fast for MFMA B).
// ---------------------------------------------------------------------------
__global__ __launch_bounds__(256) void wtrans_kernel(
    const float* __restrict__ W, u16* __restrict__ WT)
{
  __shared__ float tile[64 * 65];
  const int b = blockIdx.x;
  const int e = b >> 4, tt = b & 15;
  const int k0 = (tt >> 2) * 64, d0 = (tt & 3) * 64;
  const int t = threadIdx.x;
  const int j = t & 63, i0 = t >> 6;
  const float* We = W + (size_t)e * 65536;
#pragma unroll
  for (int p = 0; p < 16; ++p) {
    int i = p * 4 + i0;
    tile[i * 65 + j] = We[(size_t)(k0 + i) * 256 + d0 + j];   // coalesced on d
  }
  __syncthreads();
  u16* WTe = WT + (size_t)e * 65536;
#pragma unroll
  for (int p = 0; p < 16; ++p) {
    int d = p * 4 + i0;
    WTe[(size_t)(d0 + d) * 256 + k0 + j] = f2bf(tile[j * 65 + d]); // coalesced on k
  }
}

// ---------------------------------------------------------------------------
// Kernel 3a: per-expert exclusive scan over the 1024 chunk histograms.
// ---------------------------------------------------------------------------
__global__ __launch_bounds__(256) void scan_kernel(int* __restrict__ hist)
{
  const int e = blockIdx.x;
  const int t = threadIdx.x;
  const int lane = t & 63, w = t >> 6;
  int h[4];
#pragma unroll
  for (int i = 0; i < 4; ++i) h[i] = hist[(t * 4 + i) * 64 + e];
  int local = h[0] + h[1] + h[2] + h[3];
  int v = local;                         // inclusive wave scan
#pragma unroll
  for (int off = 1; off < 64; off <<= 1) {
    int u = __shfl_up(v, off);
    if (lane >= off) v += u;
  }
  __shared__ int wtot[4];
  if (lane == 63) wtot[w] = v;
  __syncthreads();
  int woff = 0;
  for (int i = 0; i < w; ++i) woff += wtot[i];
  int excl = woff + v - local;
  hist[(t * 4 + 0) * 64 + e] = excl;
  hist[(t * 4 + 1) * 64 + e] = excl + h[0];
  hist[(t * 4 + 2) * 64 + e] = excl + h[0] + h[1];
  hist[(t * 4 + 3) * 64 + e] = excl + h[0] + h[1] + h[2];
}

// ---------------------------------------------------------------------------
// Kernel 3b: rank. 1024 blocks x 128 thr (one slot each). Stable FIFO rank.
// ---------------------------------------------------------------------------
__global__ __launch_bounds__(128) void rank_kernel(
    const int* __restrict__ slot_eid, const int* __restrict__ base,
    int* __restrict__ slot2buf, int* __restrict__ row_token)
{
  const int c = blockIdx.x;
  const int t = threadIdx.x;
  const int s = c * 128 + t;
  const int lane = t & 63, w = t >> 6;
  const int e = slot_eid[s];
  __shared__ int hist0[64];
  if (t < 64) hist0[t] = 0;
  __syncthreads();
  int rank = 0, cnt = 0;
#pragma unroll
  for (int k = 0; k < 64; ++k) {
    int eo = __shfl(e, k);
    bool m = (eo == e);
    rank += (m && k < lane) ? 1 : 0;
    cnt  += m ? 1 : 0;
  }
  if (w == 0 && rank == cnt - 1) hist0[e] = cnt;   // last lane of its expert
  __syncthreads();
  int g = base[c * 64 + e] + rank + (w ? hist0[e] : 0);
  if (g < CAP) {
    slot2buf[s] = e * CAP + g;
    row_token[e * CAP + g] = s >> 1;
  } else {
    slot2buf[s] = -1;                               // capacity-dropped
  }
}

// ---------------------------------------------------------------------------
// Kernel 4: grouped expert GEMM, bf16 MFMA 16x16x32, 128x128 tile, BK=32,
// m97 structure with width-16 global_load_lds; A rows gathered via token ids.
// ---------------------------------------------------------------------------
__global__ __launch_bounds__(256) void gemm_kernel(
    const u16* __restrict__ x_bf16, const u16* __restrict__ WT,
    const int* __restrict__ row_token, u16* __restrict__ y)
{
  __shared__ u16 A_s[128 * 32];
  __shared__ u16 B_s[128 * 32];
  __shared__ int tok_s[128];

  const int b = blockIdx.x;
  const int e = b / 40;
  const int r = b % 40;
  const int m0 = (r >> 1) * 128, n0 = (r & 1) * 128;
  const int t = threadIdx.x;

  if (t < 128) tok_s[t] = row_token[e * CAP + m0 + t];
  __syncthreads();

  const int w = t >> 6, lane = t & 63;
  const int rsub = lane >> 2;
  const int koff = (lane & 3) * 8;

  const int ra0 = w * 32 + rsub;
  const int ra1 = ra0 + 16;
  const char* pa0 = (const char*)(x_bf16 + (size_t)tok_s[ra0] * 256 + koff);
  const char* pa1 = (const char*)(x_bf16 + (size_t)tok_s[ra1] * 256 + koff);
  const u16* WTe = WT + (size_t)e * 65536;
  const char* pb0 = (const char*)(WTe + (size_t)(n0 + ra0) * 256 + koff);
  const char* pb1 = (const char*)(WTe + (size_t)(n0 + ra1) * 256 + koff);

  char* ldsA0 = (char*)A_s + (w * 32) * 64;
  char* ldsA1 = (char*)A_s + (w * 32 + 16) * 64;
  char* ldsB0 = (char*)B_s + (w * 32) * 64;
  char* ldsB1 = (char*)B_s + (w * 32 + 16) * 64;

  const int wm = w & 1, wn = w >> 1;
  const int lr = lane & 15, q = lane >> 4;

  f32x4 acc[4][4];
#pragma unroll
  for (int mt = 0; mt < 4; ++mt)
#pragma unroll
    for (int nt = 0; nt < 4; ++nt) acc[mt][nt] = (f32x4){0.f, 0.f, 0.f, 0.f};

  for (int kt = 0; kt < 8; ++kt) {
    gload16(pa0, ldsA0);
    gload16(pa1, ldsA1);
    gload16(pb0, ldsB0);
    gload16(pb1, ldsB1);
    __syncthreads();
    bf16x8 af[4], bg[4];
#pragma unroll
    for (int mt = 0; mt < 4; ++mt)
      af[mt] = *(const bf16x8*)&A_s[(wm * 64 + mt * 16 + lr) * 32 + q * 8];
#pragma unroll
    for (int nt = 0; nt < 4; ++nt)
      bg[nt] = *(const bf16x8*)&B_s[(wn * 64 + nt * 16 + lr) * 32 + q * 8];
#pragma unroll
    for (int mt = 0; mt < 4; ++mt)
#pragma unroll
      for (int nt = 0; nt < 4; ++nt)
        acc[mt][nt] = __builtin_amdgcn_mfma_f32_16x16x32_bf16(
            af[mt], bg[nt], acc[mt][nt], 0, 0, 0);
    __syncthreads();
    pa0 += 64; pa1 += 64; pb0 += 64; pb1 += 64;
  }

  // C/D layout: col=lane&15, row=quad*4+reg  [verified m89/m91]
  u16* ye = y + (size_t)e * CAP * 256;
#pragma unroll
  for (int mt = 0; mt < 4; ++mt) {
    int grow = m0 + wm * 64 + mt * 16 + q * 4;
#pragma unroll
    for (int nt = 0; nt < 4; ++nt) {
      int gcol = n0 + wn * 64 + nt * 16 + lr;
#pragma unroll
      for (int rr = 0; rr < 4; ++rr)
        ye[(size_t)(grow + rr) * 256 + gcol] = f2bf(acc[mt][nt][rr]);
    }
  }
}

// ---------------------------------------------------------------------------
// Kernel 5: combine. out[t] = s0*y[p0] + s1*y[p1] (dropped -> 0). Wave/token.
// ---------------------------------------------------------------------------
__global__ __launch_bounds__(256) void combine_kernel(
    const u16* __restrict__ y, const int* __restrict__ slot2buf,
    const float* __restrict__ slot_score, float* __restrict__ out)
{
  const int tok  = blockIdx.x * 4 + (threadIdx.x >> 6);
  const int lane = threadIdx.x & 63;
  const int   p0 = slot2buf[2 * tok],   p1 = slot2buf[2 * tok + 1];
  const float s0 = slot_score[2 * tok], s1 = slot_score[2 * tok + 1];
  float o0 = 0.f, o1 = 0.f, o2 = 0.f, o3 = 0.f;
  if (p0 >= 0) {
    u16x4 h = *(const u16x4*)&y[(size_t)p0 * 256 + lane * 4];
    o0 = fmaf(s0, bf2f(h.x), o0); o1 = fmaf(s0, bf2f(h.y), o1);
    o2 = fmaf(s0, bf2f(h.z), o2); o3 = fmaf(s0, bf2f(h.w), o3);
  }
  if (p1 >= 0) {
    u16x4 h = *(const u16x4*)&y[(size_t)p1 * 256 + lane * 4];
    o0 = fmaf(s1, bf2f(h.x), o0); o1 = fmaf(s1, bf2f(h.y), o1);
    o2 = fmaf(s1, bf2f(h.z), o2); o3 = fmaf(s1, bf2f(h.w), o3);
  }
  fvec4 o = {o0, o1, o2, o3};
  *(fvec4*)&out[(size_t)tok * 256 + lane * 4] = o;
}

// ---------------------------------------------------------------------------
// Kernel 6: aux loss = mean((load/N - 1/E)^2). One wave.
// ---------------------------------------------------------------------------
__global__ __launch_bounds__(64) void aux_kernel(
    const float* __restrict__ load_g, float* __restrict__ out_aux)
{
  const int lane = threadIdx.x;
  float l = load_g[lane] * (1.0f / 65536.0f) - (1.0f / 64.0f);
  float v = l * l;
#pragma unroll
  for (int off = 1; off < 64; off <<= 1) v += __shfl_xor(v, off);
  if (lane == 0) out_aux[0] = v * (1.0f / 64.0f);
}

// ---------------------------------------------------------------------------
// Workspace layout (bytes):
//   0        slot_score f32[131072]   (512K)
//   524288   slot_eid   i32[131072]   (512K)
//   1048576  slot2buf   i32[131072]   (512K)
//   1572864  row_token  i32[163840]   (640K)  -- memset 0 each call
//   2228224  load_g     f32[64]               -- memset 0 each call
//   2359296  chunk_hist i32[1024*64]  (256K)  -- fully written by gating
//   4194304  x_bf16     u16[16777216] (32M)
//   37748736 WT         u16[4194304]  (8M)
//   46137344 y          u16[41943040] (80M)
// total ~124 MB
// ---------------------------------------------------------------------------
extern "C" void kernel_launch(void* const* d_in, const int* in_sizes, int n_in,
                              void* d_out, int out_size, void* d_ws, size_t ws_size,
                              hipStream_t stream)
{
  const float* x  = (const float*)d_in[0];
  const float* Wg = (const float*)d_in[1];
  const float* We = (const float*)d_in[2];
  float* out = (float*)d_out;

  char* ws = (char*)d_ws;
  float* slot_score = (float*)(ws + 0);
  int*   slot_eid   = (int*)(ws + 524288);
  int*   slot2buf   = (int*)(ws + 1048576);
  int*   row_token  = (int*)(ws + 1572864);
  float* load_g     = (float*)(ws + 2228224);
  int*   chunk_hist = (int*)(ws + 2359296);
  u16*   x_bf16     = (u16*)(ws + 4194304);
  u16*   WT         = (u16*)(ws + 37748736);
  u16*   y          = (u16*)(ws + 46137344);

  hipMemsetAsync(row_token, 0, 655360, stream);   // unfilled rows -> token 0
  hipMemsetAsync(load_g, 0, 256, stream);

  gating_kernel<<<1024, 256, 0, stream>>>(x, Wg, x_bf16, slot_score, slot_eid,
                                          load_g, chunk_hist);
  wtrans_kernel<<<1024, 256, 0, stream>>>(We, WT);
  scan_kernel<<<64, 256, 0, stream>>>(chunk_hist);
  rank_kernel<<<1024, 128, 0, stream>>>(slot_eid, chunk_hist, slot2buf, row_token);
  gemm_kernel<<<2560, 256, 0, stream>>>(x_bf16, WT, row_token, y);
  combine_kernel<<<16384, 256, 0, stream>>>(y, slot2buf, slot_score, out);
  aux_kernel<<<1, 64, 0, stream>>>(load_g, out + 16777216);
}